// Round 3
// baseline (5967.483 us; speedup 1.0000x reference)
//
#include <hip/hip_runtime.h>
#include <hip/hip_bf16.h>
#include <hip/hip_cooperative_groups.h>

namespace cg = cooperative_groups;

#define BATCH 64
#define NPIX 196
#define ENCD 2048
#define ATTD 512
#define DECD 512
#define EMBD 512
#define NVOCAB 10000
#define TSTEPS 24
#define KX 3072

typedef short bf16x8 __attribute__((ext_vector_type(8)));
typedef float f32x4 __attribute__((ext_vector_type(4)));

__device__ inline ushort f2bf(float f) {
    union { float f; unsigned u; } v; v.f = f;
    unsigned r = (v.u + 0x7fff + ((v.u >> 16) & 1)) >> 16;
    return (ushort)r;
}
__device__ inline float bf2f(ushort u) {
    union { unsigned u; float f; } v; v.u = ((unsigned)u) << 16;
    return v.f;
}

// ---------------- meta ----------------
__global__ void k_meta(const int* __restrict__ caps, const int* __restrict__ lens,
                       float* __restrict__ cap_out, float* __restrict__ len_out) {
    int i = blockIdx.x * 256 + threadIdx.x;
    if (i < BATCH * 25) cap_out[i] = (float)caps[i];
    if (i < BATCH)      len_out[i] = (float)(lens[i] - 1);
}

// ---------------- mean over 196 positions ----------------
__global__ void k_mean(const float* __restrict__ enc, float* __restrict__ mean_enc) {
    int b = blockIdx.x;
    int e = blockIdx.y * 256 + threadIdx.x;
    const float* base = enc + (size_t)b * NPIX * ENCD + e;
    float s = 0.f;
    for (int p = 0; p < NPIX; ++p) s += base[(size_t)p * ENCD];
    mean_enc[(size_t)b * ENCD + e] = s * (1.0f / NPIX);
}

// ---------------- h0/c0 init ----------------
__global__ __launch_bounds__(256) void k_init_hc(
        const float* __restrict__ mean_enc,
        const float* __restrict__ Wh, const float* __restrict__ bh,
        const float* __restrict__ Wc, const float* __restrict__ bc,
        ushort* __restrict__ hbf, float* __restrict__ c) {
    __shared__ float m[4][ENCD];
    int bg = blockIdx.x * 4;
    for (int i = threadIdx.x; i < 4 * ENCD; i += 256)
        m[i >> 11][i & 2047] = mean_enc[(size_t)(bg + (i >> 11)) * ENCD + (i & 2047)];
    __syncthreads();
    int j = blockIdx.y * 256 + threadIdx.x;
    const float* W; const float* bias; int col;
    bool isH = j < DECD;
    if (isH) { W = Wh; bias = bh; col = j; }
    else     { W = Wc; bias = bc; col = j - DECD; }
    float acc[4] = {0.f, 0.f, 0.f, 0.f};
    for (int k = 0; k < ENCD; ++k) {
        float w = W[(size_t)k * DECD + col];
#pragma unroll
        for (int q = 0; q < 4; ++q) acc[q] += m[q][k] * w;
    }
#pragma unroll
    for (int q = 0; q < 4; ++q) {
        float v = acc[q] + bias[col];
        if (isH) hbf[(size_t)(bg + q) * DECD + col] = f2bf(v);
        else     c[(size_t)(bg + q) * DECD + col] = v;
    }
}

// ---------------- WTj[j][k] bf16 ----------------
__global__ __launch_bounds__(256) void k_cp_wtj(const float* __restrict__ Wih,
                                                const float* __restrict__ Whh,
                                                ushort* __restrict__ WTj) {
    int j = blockIdx.x;
    for (int k = threadIdx.x; k < KX; k += 256) {
        float v = (k < 2560) ? Wih[(size_t)j * 2560 + k] : Whh[(size_t)j * 512 + (k - 2560)];
        WTj[(size_t)j * KX + k] = f2bf(v);
    }
}

// ---------------- transposes to [n][k] bf16 ----------------
__global__ __launch_bounds__(256) void k_tr_bpre(const float* __restrict__ Wd,
                                                 const float* __restrict__ Wfb,
                                                 ushort* __restrict__ out) {
    __shared__ float tile[32][33];
    int nb = blockIdx.x * 32, kb = blockIdx.y * 32;
    int tx = threadIdx.x & 31, ty = threadIdx.x >> 5;
    for (int i = 0; i < 32; i += 8) {
        int k = kb + ty + i, n = nb + tx;
        float v = (n < ATTD) ? Wd[(size_t)k * ATTD + n] : Wfb[(size_t)k * ENCD + (n - ATTD)];
        tile[ty + i][tx] = v;
    }
    __syncthreads();
    for (int i = 0; i < 32; i += 8)
        out[(size_t)(nb + ty + i) * 512 + kb + tx] = f2bf(tile[tx][ty + i]);
}

__global__ __launch_bounds__(256) void k_tr_wfct(const float* __restrict__ Wfc,
                                                 ushort* __restrict__ out) {
    __shared__ float tile[32][33];
    int nb = blockIdx.x * 32, kb = blockIdx.y * 32;
    int tx = threadIdx.x & 31, ty = threadIdx.x >> 5;
    for (int i = 0; i < 32; i += 8) {
        int k = kb + ty + i, n = nb + tx;
        float v = (n < NVOCAB) ? Wfc[(size_t)k * NVOCAB + n] : 0.f;
        tile[ty + i][tx] = v;
    }
    __syncthreads();
    for (int i = 0; i < 32; i += 8)
        out[(size_t)(nb + ty + i) * 512 + kb + tx] = f2bf(tile[tx][ty + i]);
}

__global__ __launch_bounds__(256) void k_tr_wet(const float* __restrict__ We,
                                                ushort* __restrict__ out) {
    __shared__ float tile[32][33];
    int nb = blockIdx.x * 32, kb = blockIdx.y * 32;
    int tx = threadIdx.x & 31, ty = threadIdx.x >> 5;
    for (int i = 0; i < 32; i += 8) {
        int k = kb + ty + i, n = nb + tx;
        tile[ty + i][tx] = We[(size_t)k * ATTD + n];
    }
    __syncthreads();
    for (int i = 0; i < 32; i += 8)
        out[(size_t)(nb + ty + i) * ENCD + kb + tx] = f2bf(tile[tx][ty + i]);
}

// ---------------- emb gather: embAll[t*64+b][k] ----------------
__global__ __launch_bounds__(256) void k_embgather(const int* __restrict__ caps,
                                                   const float* __restrict__ emb,
                                                   ushort* __restrict__ embAll) {
    int r = blockIdx.x;              // 0..1535, r = t*64 + b
    int b = r & 63, t = r >> 6;
    int tok = caps[b * 25 + t];
    for (int k = threadIdx.x; k < 512; k += 256)
        embAll[(size_t)r * 512 + k] = f2bf(emb[(size_t)tok * 512 + k]);
}

// ---------------- embpart = embAll @ WTj[:, :512]^T  (1536 x 2048) ----------------
__global__ __launch_bounds__(256) void k_embpart(const ushort* __restrict__ embAll,
                                                 const ushort* __restrict__ WTj,
                                                 float* __restrict__ embpart) {
    int w = threadIdx.x >> 6, l = threadIdx.x & 63;
    int m = l & 15, kg = l >> 4;
    int r0 = blockIdx.x * 64;
    int n = blockIdx.y * 64 + w * 16 + m;
    const ushort* B = WTj + (size_t)n * KX + kg * 8;
    const ushort* A = embAll + (size_t)(r0 + m) * 512 + kg * 8;
    f32x4 acc[4] = {};
#pragma unroll 4
    for (int k0 = 0; k0 < 512; k0 += 32) {
        bf16x8 bfr = *(const bf16x8*)(B + k0);
#pragma unroll
        for (int mf = 0; mf < 4; ++mf) {
            bf16x8 afr = *(const bf16x8*)(A + mf * 16 * 512 + k0);
            acc[mf] = __builtin_amdgcn_mfma_f32_16x16x32_bf16(afr, bfr, acc[mf], 0, 0, 0);
        }
    }
#pragma unroll
    for (int mf = 0; mf < 4; ++mf)
#pragma unroll
        for (int r = 0; r < 4; ++r)
            embpart[(size_t)(r0 + mf * 16 + kg * 4 + r) * 2048 + n] = acc[mf][r];
}

// ---------------- one-time: att1 = enc @ We + be ----------------
__global__ __launch_bounds__(256) void k_att1(
        const float* __restrict__ enc, const ushort* __restrict__ WeT,
        const float* __restrict__ be, ushort* __restrict__ att1b) {
    int w = threadIdx.x >> 6, l = threadIdx.x & 63;
    int wr = w >> 1, wc = w & 1;
    int m0 = blockIdx.x * 128 + wr * 64;
    int n0 = blockIdx.y * 128 + wc * 64;
    int ml = l & 15, kg = l >> 4;
    const float*  aBase = enc + (size_t)(m0 + ml) * ENCD + kg * 8;
    const ushort* bBase = WeT + (size_t)(n0 + ml) * ENCD + kg * 8;
    f32x4 acc[4][4] = {};
    for (int k0 = 0; k0 < ENCD; k0 += 32) {
        bf16x8 bfr[4], afr[4];
#pragma unroll
        for (int nf = 0; nf < 4; ++nf)
            bfr[nf] = *(const bf16x8*)(bBase + (size_t)nf * 16 * ENCD + k0);
#pragma unroll
        for (int mf = 0; mf < 4; ++mf) {
            const float* ap = aBase + (size_t)mf * 16 * ENCD + k0;
            float4 f0 = *(const float4*)ap;
            float4 f1 = *(const float4*)(ap + 4);
            bf16x8 a;
            a[0] = f2bf(f0.x); a[1] = f2bf(f0.y); a[2] = f2bf(f0.z); a[3] = f2bf(f0.w);
            a[4] = f2bf(f1.x); a[5] = f2bf(f1.y); a[6] = f2bf(f1.z); a[7] = f2bf(f1.w);
            afr[mf] = a;
        }
#pragma unroll
        for (int mf = 0; mf < 4; ++mf)
#pragma unroll
            for (int nf = 0; nf < 4; ++nf)
                acc[mf][nf] = __builtin_amdgcn_mfma_f32_16x16x32_bf16(afr[mf], bfr[nf], acc[mf][nf], 0, 0, 0);
    }
#pragma unroll
    for (int mf = 0; mf < 4; ++mf)
#pragma unroll
        for (int nf = 0; nf < 4; ++nf) {
            int col = n0 + nf * 16 + ml;
            float bias = be[col];
#pragma unroll
            for (int r = 0; r < 4; ++r) {
                int row = m0 + mf * 16 + kg * 4 + r;
                att1b[(size_t)row * ATTD + col] = f2bf(acc[mf][nf][r] + bias);
            }
        }
}

// ---------------- the cooperative mega-kernel: all 24 steps ----------------
struct KP {
    const float* enc;
    const int* caps;
    const int* lens;
    const float* vatt;
    const float* bv;
    const float* bd;
    const float* bfb;
    const float* bfc;
    const float* bih;
    const float* bhh;
    const ushort* att1b;
    const ushort* WTj;
    const ushort* WfcT;
    const ushort* BpreT;
    const float* embpart;
    ushort* ctxb;
    ushort* hbf;
    float* c;
    float* att2;
    float* gatebuf;   // sigmoid(h@Wfb+b)
    float* hpart;     // h @ Whh^T
    float* alpha;     // normalized, unmasked
    float* pred;
    float* alpha_out;
};

__global__ __launch_bounds__(256) void k_loop(KP p) {
    cg::grid_group grid = cg::this_grid();
    __shared__ float smem[64 * 68];
    int blk = blockIdx.x;
    int tid = threadIdx.x;
    int w = tid >> 6, l = tid & 63;
    int m = l & 15, kg = l >> 4;

    for (int t = 0; t <= TSTEPS; ++t) {
        // ---- phase 1: h-GEMMs (blocks 0..228) ----
        if (blk < 229) {
            bool run = (blk < 157) ? (t >= 1) : (t < TSTEPS);
            if (run) {
                const ushort* B;
                int n;
                if (blk < 157)      { n = blk * 64 + w * 16 + m;        B = p.WfcT  + (size_t)n * 512; }
                else if (blk < 197) { n = (blk - 157) * 64 + w * 16 + m; B = p.BpreT + (size_t)n * 512; }
                else                { n = (blk - 197) * 64 + w * 16 + m; B = p.WTj   + (size_t)n * KX + 2560; }
                const ushort* A = p.hbf + (size_t)m * 512 + kg * 8;
                B += kg * 8;
                f32x4 acc[4] = {};
#pragma unroll 4
                for (int k0 = 0; k0 < 512; k0 += 32) {
                    bf16x8 bfr = *(const bf16x8*)(B + k0);
#pragma unroll
                    for (int mf = 0; mf < 4; ++mf) {
                        bf16x8 afr = *(const bf16x8*)(A + mf * 16 * 512 + k0);
                        acc[mf] = __builtin_amdgcn_mfma_f32_16x16x32_bf16(afr, bfr, acc[mf], 0, 0, 0);
                    }
                }
                if (blk < 157) {
                    if (n < NVOCAB) {
                        float bias = p.bfc[n];
#pragma unroll
                        for (int mf = 0; mf < 4; ++mf)
#pragma unroll
                            for (int r = 0; r < 4; ++r) {
                                int b = mf * 16 + kg * 4 + r;
                                bool act = (t - 1) < (p.lens[b] - 1);
                                p.pred[((size_t)b * TSTEPS + (t - 1)) * NVOCAB + n] =
                                    act ? acc[mf][r] + bias : 0.f;
                            }
                    }
                } else if (blk < 197) {
                    if (n < ATTD) {
                        float bias = p.bd[n];
#pragma unroll
                        for (int mf = 0; mf < 4; ++mf)
#pragma unroll
                            for (int r = 0; r < 4; ++r) {
                                int b = mf * 16 + kg * 4 + r;
                                p.att2[(size_t)b * ATTD + n] = acc[mf][r] + bias;
                            }
                    } else {
                        int e = n - ATTD;
                        float bias = p.bfb[e];
#pragma unroll
                        for (int mf = 0; mf < 4; ++mf)
#pragma unroll
                            for (int r = 0; r < 4; ++r) {
                                int b = mf * 16 + kg * 4 + r;
                                float v = acc[mf][r] + bias;
                                p.gatebuf[(size_t)b * ENCD + e] = 1.f / (1.f + __expf(-v));
                            }
                    }
                } else {
#pragma unroll
                    for (int mf = 0; mf < 4; ++mf)
#pragma unroll
                        for (int r = 0; r < 4; ++r) {
                            int b = mf * 16 + kg * 4 + r;
                            p.hpart[(size_t)b * 2048 + n] = acc[mf][r];
                        }
                }
            }
        }
        if (t == TSTEPS) break;
        grid.sync();

        // ---- phase 2: softmax (blocks 0..63) ----
        if (blk < 64) {
            int b = blk;
            float* ev = smem;             // [196]
            float* inv_s = smem + 200;
            float a2r[8], vvr[8];
            const float* att2b = p.att2 + (size_t)b * ATTD;
#pragma unroll
            for (int i = 0; i < 8; ++i) {
                a2r[i] = att2b[l * 8 + i];
                vvr[i] = p.vatt[l * 8 + i];
            }
            for (int pp = w; pp < NPIX; pp += 4) {
                const ushort* r = p.att1b + ((size_t)b * NPIX + pp) * ATTD + l * 8;
                bf16x8 f = *(const bf16x8*)r;
                float s = 0.f;
#pragma unroll
                for (int i = 0; i < 8; ++i)
                    s += fmaxf(bf2f(f[i]) + a2r[i], 0.f) * vvr[i];
                for (int off = 32; off > 0; off >>= 1) s += __shfl_down(s, off);
                if (l == 0) ev[pp] = s + p.bv[0];
            }
            __syncthreads();
            if (w == 0) {
                float mx = -1e30f;
                for (int pp = l; pp < NPIX; pp += 64) mx = fmaxf(mx, ev[pp]);
                for (int off = 32; off > 0; off >>= 1) mx = fmaxf(mx, __shfl_down(mx, off));
                mx = __shfl(mx, 0);
                float s = 0.f;
                for (int pp = l; pp < NPIX; pp += 64) {
                    float e_ = __expf(ev[pp] - mx);
                    ev[pp] = e_;
                    s += e_;
                }
                for (int off = 32; off > 0; off >>= 1) s += __shfl_down(s, off);
                if (l == 0) *inv_s = 1.0f / s;
            }
            __syncthreads();
            float inv = *inv_s;
            bool active = t < (p.lens[b] - 1);
            for (int pp = tid; pp < NPIX; pp += 256) {
                float a = ev[pp] * inv;
                p.alpha[(size_t)b * NPIX + pp] = a;
                p.alpha_out[((size_t)b * TSTEPS + t) * NPIX + pp] = active ? a : 0.f;
            }
        }
        grid.sync();

        // ---- phase 3: context (all 256 blocks) ----
        {
            int b = blk >> 2, q = blk & 3;
            float* sa = smem;
            for (int i = tid; i < NPIX; i += 256) sa[i] = p.alpha[(size_t)b * NPIX + i];
            __syncthreads();
            int e = q * 512 + tid * 2;
            const float* ep = p.enc + (size_t)b * NPIX * ENCD + e;
            float s0 = 0.f, s1 = 0.f;
#pragma unroll 4
            for (int pp = 0; pp < NPIX; ++pp) {
                float2 v = *(const float2*)(ep + (size_t)pp * ENCD);
                float al = sa[pp];
                s0 += al * v.x; s1 += al * v.y;
            }
            float2 gg = *(const float2*)(p.gatebuf + (size_t)b * ENCD + e);
            ushort2 o;
            o.x = f2bf(s0 * gg.x);
            o.y = f2bf(s1 * gg.y);
            *(ushort2*)(p.ctxb + (size_t)b * ENCD + e) = o;
            __syncthreads();
        }
        grid.sync();

        // ---- phase 4: gates GEMM (ctx part) + LSTM pointwise (blocks 0..31) ----
        if (blk < 32) {
            int g = blk;
            int jcol = w * 512 + g * 16 + m;
            const ushort* B = p.WTj + (size_t)jcol * KX + 512 + kg * 8;
            const ushort* A = p.ctxb + (size_t)m * 2048 + kg * 8;
            f32x4 acc[4] = {};
#pragma unroll 4
            for (int k0 = 0; k0 < 2048; k0 += 32) {
                bf16x8 bfr = *(const bf16x8*)(B + k0);
#pragma unroll
                for (int mf = 0; mf < 4; ++mf) {
                    bf16x8 afr = *(const bf16x8*)(A + mf * 16 * 2048 + k0);
                    acc[mf] = __builtin_amdgcn_mfma_f32_16x16x32_bf16(afr, bfr, acc[mf], 0, 0, 0);
                }
            }
            float* gt = smem;   // [64][68]
#pragma unroll
            for (int mf = 0; mf < 4; ++mf)
#pragma unroll
                for (int r = 0; r < 4; ++r)
                    gt[(mf * 16 + kg * 4 + r) * 68 + w * 16 + m] = acc[mf][r];
            __syncthreads();
            const float* ebase = p.embpart + ((size_t)t * 64) * 2048;
            for (int idx = tid; idx < 1024; idx += 256) {
                int b = idx >> 4, r = idx & 15;
                int d = g * 16 + r;
                if (t < p.lens[b] - 1) {
                    const float* eb = ebase + (size_t)b * 2048;
                    const float* hp = p.hpart + (size_t)b * 2048;
                    float gi = gt[b * 68 + r]      + hp[d]        + eb[d]        + p.bih[d]        + p.bhh[d];
                    float gf = gt[b * 68 + 16 + r] + hp[512 + d]  + eb[512 + d]  + p.bih[512 + d]  + p.bhh[512 + d];
                    float gg = gt[b * 68 + 32 + r] + hp[1024 + d] + eb[1024 + d] + p.bih[1024 + d] + p.bhh[1024 + d];
                    float go = gt[b * 68 + 48 + r] + hp[1536 + d] + eb[1536 + d] + p.bih[1536 + d] + p.bhh[1536 + d];
                    float cc = p.c[(size_t)b * DECD + d];
                    float si = 1.f / (1.f + __expf(-gi));
                    float sf = 1.f / (1.f + __expf(-gf));
                    float so = 1.f / (1.f + __expf(-go));
                    float cn = sf * cc + si * tanhf(gg);
                    float hn = so * tanhf(cn);
                    p.c[(size_t)b * DECD + d] = cn;
                    p.hbf[(size_t)b * DECD + d] = f2bf(hn);
                }
            }
            __syncthreads();
        }
        grid.sync();
    }
}

extern "C" void kernel_launch(void* const* d_in, const int* in_sizes, int n_in,
                              void* d_out, int out_size, void* d_ws, size_t ws_size,
                              hipStream_t stream) {
    const float* enc  = (const float*)d_in[0];
    const int*   caps = (const int*)d_in[1];
    const int*   lens = (const int*)d_in[2];
    const float* emb  = (const float*)d_in[3];
    const float* We   = (const float*)d_in[4];
    const float* be   = (const float*)d_in[5];
    const float* Wd   = (const float*)d_in[6];
    const float* bd   = (const float*)d_in[7];
    const float* vatt = (const float*)d_in[8];
    const float* bv   = (const float*)d_in[9];
    const float* Wih  = (const float*)d_in[10];
    const float* bih  = (const float*)d_in[11];
    const float* Whh  = (const float*)d_in[12];
    const float* bhh  = (const float*)d_in[13];
    const float* Winh = (const float*)d_in[14];
    const float* binh = (const float*)d_in[15];
    const float* Winc = (const float*)d_in[16];
    const float* binc = (const float*)d_in[17];
    const float* Wfb  = (const float*)d_in[18];
    const float* bfb  = (const float*)d_in[19];
    const float* Wfc  = (const float*)d_in[20];
    const float* bfc  = (const float*)d_in[21];

    float* out       = (float*)d_out;
    float* pred_out  = out;
    float* cap_out   = out + 15360000;
    float* len_out   = out + 15361600;
    float* alpha_out = out + 15361664;

    char* pw = (char*)d_ws;
    ushort* att1b  = (ushort*)pw; pw += (size_t)12544 * 512 * 2;
    ushort* WTj    = (ushort*)pw; pw += (size_t)2048 * KX * 2;
    ushort* WfcT   = (ushort*)pw; pw += (size_t)10048 * 512 * 2;
    ushort* BpreT  = (ushort*)pw; pw += (size_t)2560 * 512 * 2;
    ushort* WeT    = (ushort*)pw; pw += (size_t)512 * 2048 * 2;
    ushort* embAll = (ushort*)pw; pw += (size_t)1536 * 512 * 2;
    float* embpart = (float*)pw;  pw += (size_t)1536 * 2048 * 4;
    ushort* ctxb   = (ushort*)pw; pw += (size_t)64 * 2048 * 2;
    ushort* hbf    = (ushort*)pw; pw += (size_t)64 * 512 * 2;
    float* att2    = (float*)pw;  pw += (size_t)64 * 512 * 4;
    float* gatebuf = (float*)pw;  pw += (size_t)64 * 2048 * 4;
    float* hpart   = (float*)pw;  pw += (size_t)64 * 2048 * 4;
    float* alpha   = (float*)pw;  pw += (size_t)64 * 196 * 4;
    float* c       = (float*)pw;  pw += (size_t)64 * 512 * 4;
    float* mean    = (float*)pw;  pw += (size_t)64 * 2048 * 4;

    k_meta<<<7, 256, 0, stream>>>(caps, lens, cap_out, len_out);
    k_mean<<<dim3(BATCH, 8), 256, 0, stream>>>(enc, mean);
    k_init_hc<<<dim3(16, 4), 256, 0, stream>>>(mean, Winh, binh, Winc, binc, hbf, c);
    k_cp_wtj<<<2048, 256, 0, stream>>>(Wih, Whh, WTj);
    k_tr_bpre<<<dim3(80, 16), 256, 0, stream>>>(Wd, Wfb, BpreT);
    k_tr_wfct<<<dim3(314, 16), 256, 0, stream>>>(Wfc, WfcT);
    k_tr_wet<<<dim3(16, 64), 256, 0, stream>>>(We, WeT);
    k_embgather<<<1536, 256, 0, stream>>>(caps, emb, embAll);
    k_att1<<<dim3(98, 4), 256, 0, stream>>>(enc, WeT, be, att1b);
    k_embpart<<<dim3(24, 32), 256, 0, stream>>>(embAll, WTj, embpart);

    KP kp;
    kp.enc = enc; kp.caps = caps; kp.lens = lens; kp.vatt = vatt; kp.bv = bv;
    kp.bd = bd; kp.bfb = bfb; kp.bfc = bfc; kp.bih = bih; kp.bhh = bhh;
    kp.att1b = att1b; kp.WTj = WTj; kp.WfcT = WfcT; kp.BpreT = BpreT;
    kp.embpart = embpart; kp.ctxb = ctxb; kp.hbf = hbf; kp.c = c;
    kp.att2 = att2; kp.gatebuf = gatebuf; kp.hpart = hpart; kp.alpha = alpha;
    kp.pred = pred_out; kp.alpha_out = alpha_out;

    void* args[] = { &kp };
    hipLaunchCooperativeKernel((void*)k_loop, dim3(256), dim3(256), args, 0, stream);
}

// Round 4
// 2891.256 us; speedup vs baseline: 2.0640x; 2.0640x over previous
//
#include <hip/hip_runtime.h>
#include <hip/hip_bf16.h>

#define BATCH 64
#define NPIX 196
#define ENCD 2048
#define ATTD 512
#define DECD 512
#define EMBD 512
#define NVOCAB 10000
#define TSTEPS 24
#define KX 3072
#define NPAD 10112   // vocab padded to 79*128

typedef short bf16x8 __attribute__((ext_vector_type(8)));
typedef float f32x4 __attribute__((ext_vector_type(4)));

__device__ inline ushort f2bf(float f) {
    union { float f; unsigned u; } v; v.f = f;
    unsigned r = (v.u + 0x7fff + ((v.u >> 16) & 1)) >> 16;
    return (ushort)r;
}
__device__ inline float bf2f(ushort u) {
    union { unsigned u; float f; } v; v.u = ((unsigned)u) << 16;
    return v.f;
}

// ---------------- meta ----------------
__global__ void k_meta(const int* __restrict__ caps, const int* __restrict__ lens,
                       float* __restrict__ cap_out, float* __restrict__ len_out) {
    int i = blockIdx.x * 256 + threadIdx.x;
    if (i < BATCH * 25) cap_out[i] = (float)caps[i];
    if (i < BATCH)      len_out[i] = (float)(lens[i] - 1);
}

// ---------------- enc fp32 -> bf16 ----------------
__global__ void k_encconv(const float* __restrict__ enc, ushort* __restrict__ encb) {
    size_t i = ((size_t)blockIdx.x * 256 + threadIdx.x) * 8;
    float4 f0 = *(const float4*)(enc + i);
    float4 f1 = *(const float4*)(enc + i + 4);
    union { bf16x8 v; ushort u[8]; } o;
    o.u[0] = f2bf(f0.x); o.u[1] = f2bf(f0.y); o.u[2] = f2bf(f0.z); o.u[3] = f2bf(f0.w);
    o.u[4] = f2bf(f1.x); o.u[5] = f2bf(f1.y); o.u[6] = f2bf(f1.z); o.u[7] = f2bf(f1.w);
    *(bf16x8*)(encb + i) = o.v;
}

// ---------------- mean over 196 positions (fp32 enc) ----------------
__global__ void k_mean(const float* __restrict__ enc, float* __restrict__ mean_enc) {
    int b = blockIdx.x;
    int e = blockIdx.y * 256 + threadIdx.x;
    const float* base = enc + (size_t)b * NPIX * ENCD + e;
    float s = 0.f;
    for (int p = 0; p < NPIX; ++p) s += base[(size_t)p * ENCD];
    mean_enc[(size_t)b * ENCD + e] = s * (1.0f / NPIX);
}

// ---------------- h0/c0 init ----------------
__global__ __launch_bounds__(256) void k_init_hc(
        const float* __restrict__ mean_enc,
        const float* __restrict__ Wh, const float* __restrict__ bh,
        const float* __restrict__ Wc, const float* __restrict__ bc,
        ushort* __restrict__ hbf, float* __restrict__ c) {
    __shared__ float m[4][ENCD];
    int bg = blockIdx.x * 4;
    for (int i = threadIdx.x; i < 4 * ENCD; i += 256)
        m[i >> 11][i & 2047] = mean_enc[(size_t)(bg + (i >> 11)) * ENCD + (i & 2047)];
    __syncthreads();
    int j = blockIdx.y * 256 + threadIdx.x;
    const float* W; const float* bias; int col;
    bool isH = j < DECD;
    if (isH) { W = Wh; bias = bh; col = j; }
    else     { W = Wc; bias = bc; col = j - DECD; }
    float acc[4] = {0.f, 0.f, 0.f, 0.f};
    for (int k = 0; k < ENCD; ++k) {
        float w = W[(size_t)k * DECD + col];
#pragma unroll
        for (int q = 0; q < 4; ++q) acc[q] += m[q][k] * w;
    }
#pragma unroll
    for (int q = 0; q < 4; ++q) {
        float v = acc[q] + bias[col];
        if (isH) hbf[(size_t)(bg + q) * DECD + col] = f2bf(v);
        else     c[(size_t)(bg + q) * DECD + col] = v;
    }
}

// ---------------- WTj[j][k] bf16 ----------------
__global__ __launch_bounds__(256) void k_cp_wtj(const float* __restrict__ Wih,
                                                const float* __restrict__ Whh,
                                                ushort* __restrict__ WTj) {
    int j = blockIdx.x;
    for (int k = threadIdx.x; k < KX; k += 256) {
        float v = (k < 2560) ? Wih[(size_t)j * 2560 + k] : Whh[(size_t)j * 512 + (k - 2560)];
        WTj[(size_t)j * KX + k] = f2bf(v);
    }
}

// ---------------- transposes to [n][k] bf16 ----------------
__global__ __launch_bounds__(256) void k_tr_bpre(const float* __restrict__ Wd,
                                                 const float* __restrict__ Wfb,
                                                 ushort* __restrict__ out) {
    __shared__ float tile[32][33];
    int nb = blockIdx.x * 32, kb = blockIdx.y * 32;
    int tx = threadIdx.x & 31, ty = threadIdx.x >> 5;
    for (int i = 0; i < 32; i += 8) {
        int k = kb + ty + i, n = nb + tx;
        float v = (n < ATTD) ? Wd[(size_t)k * ATTD + n] : Wfb[(size_t)k * ENCD + (n - ATTD)];
        tile[ty + i][tx] = v;
    }
    __syncthreads();
    for (int i = 0; i < 32; i += 8)
        out[(size_t)(nb + ty + i) * 512 + kb + tx] = f2bf(tile[tx][ty + i]);
}

__global__ __launch_bounds__(256) void k_tr_wfct(const float* __restrict__ Wfc,
                                                 ushort* __restrict__ out) {
    __shared__ float tile[32][33];
    int nb = blockIdx.x * 32, kb = blockIdx.y * 32;
    int tx = threadIdx.x & 31, ty = threadIdx.x >> 5;
    for (int i = 0; i < 32; i += 8) {
        int k = kb + ty + i, n = nb + tx;
        float v = (n < NVOCAB) ? Wfc[(size_t)k * NVOCAB + n] : 0.f;
        tile[ty + i][tx] = v;
    }
    __syncthreads();
    for (int i = 0; i < 32; i += 8)
        out[(size_t)(nb + ty + i) * 512 + kb + tx] = f2bf(tile[tx][ty + i]);
}

__global__ __launch_bounds__(256) void k_tr_wet(const float* __restrict__ We,
                                                ushort* __restrict__ out) {
    __shared__ float tile[32][33];
    int nb = blockIdx.x * 32, kb = blockIdx.y * 32;
    int tx = threadIdx.x & 31, ty = threadIdx.x >> 5;
    for (int i = 0; i < 32; i += 8) {
        int k = kb + ty + i, n = nb + tx;
        tile[ty + i][tx] = We[(size_t)k * ATTD + n];
    }
    __syncthreads();
    for (int i = 0; i < 32; i += 8)
        out[(size_t)(nb + ty + i) * ENCD + kb + tx] = f2bf(tile[tx][ty + i]);
}

// ---------------- emb gather ----------------
__global__ __launch_bounds__(256) void k_embgather(const int* __restrict__ caps,
                                                   const float* __restrict__ emb,
                                                   ushort* __restrict__ embAll) {
    int r = blockIdx.x;              // r = t*64 + b
    int b = r & 63, t = r >> 6;
    int tok = caps[b * 25 + t];
    for (int k = threadIdx.x; k < 512; k += 256)
        embAll[(size_t)r * 512 + k] = f2bf(emb[(size_t)tok * 512 + k]);
}

// ---------------- embpart (bf16) = embAll @ WTj[:, :512]^T ----------------
__global__ __launch_bounds__(256) void k_embpart(const ushort* __restrict__ embAll,
                                                 const ushort* __restrict__ WTj,
                                                 ushort* __restrict__ embpartb) {
    int w = threadIdx.x >> 6, l = threadIdx.x & 63;
    int m = l & 15, kg = l >> 4;
    int r0 = blockIdx.x * 64;
    int n = blockIdx.y * 64 + w * 16 + m;
    const ushort* B = WTj + (size_t)n * KX + kg * 8;
    const ushort* A = embAll + (size_t)(r0 + m) * 512 + kg * 8;
    f32x4 acc[4] = {};
#pragma unroll 4
    for (int k0 = 0; k0 < 512; k0 += 32) {
        bf16x8 bfr = *(const bf16x8*)(B + k0);
#pragma unroll
        for (int mf = 0; mf < 4; ++mf) {
            bf16x8 afr = *(const bf16x8*)(A + mf * 16 * 512 + k0);
            acc[mf] = __builtin_amdgcn_mfma_f32_16x16x32_bf16(afr, bfr, acc[mf], 0, 0, 0);
        }
    }
#pragma unroll
    for (int mf = 0; mf < 4; ++mf)
#pragma unroll
        for (int r = 0; r < 4; ++r)
            embpartb[(size_t)(r0 + mf * 16 + kg * 4 + r) * 2048 + n] = f2bf(acc[mf][r]);
}

// ---------------- one-time: att1 = enc @ We + be ----------------
template<bool BF>
__global__ __launch_bounds__(256) void k_att1(
        const float* __restrict__ enc, const ushort* __restrict__ encb,
        const ushort* __restrict__ WeT, const float* __restrict__ be,
        ushort* __restrict__ att1b) {
    int w = threadIdx.x >> 6, l = threadIdx.x & 63;
    int wr = w >> 1, wc = w & 1;
    int m0 = blockIdx.x * 128 + wr * 64;
    int n0 = blockIdx.y * 128 + wc * 64;
    int ml = l & 15, kg = l >> 4;
    const ushort* bBase = WeT + (size_t)(n0 + ml) * ENCD + kg * 8;
    f32x4 acc[4][4] = {};
    for (int k0 = 0; k0 < ENCD; k0 += 32) {
        bf16x8 bfr[4], afr[4];
#pragma unroll
        for (int nf = 0; nf < 4; ++nf)
            bfr[nf] = *(const bf16x8*)(bBase + (size_t)nf * 16 * ENCD + k0);
#pragma unroll
        for (int mf = 0; mf < 4; ++mf) {
            if constexpr (BF) {
                const ushort* ap = encb + (size_t)(m0 + ml + mf * 16) * ENCD + kg * 8 + k0;
                afr[mf] = *(const bf16x8*)ap;
            } else {
                const float* ap = enc + (size_t)(m0 + ml + mf * 16) * ENCD + kg * 8 + k0;
                float4 f0 = *(const float4*)ap;
                float4 f1 = *(const float4*)(ap + 4);
                bf16x8 a;
                a[0] = f2bf(f0.x); a[1] = f2bf(f0.y); a[2] = f2bf(f0.z); a[3] = f2bf(f0.w);
                a[4] = f2bf(f1.x); a[5] = f2bf(f1.y); a[6] = f2bf(f1.z); a[7] = f2bf(f1.w);
                afr[mf] = a;
            }
        }
#pragma unroll
        for (int mf = 0; mf < 4; ++mf)
#pragma unroll
            for (int nf = 0; nf < 4; ++nf)
                acc[mf][nf] = __builtin_amdgcn_mfma_f32_16x16x32_bf16(afr[mf], bfr[nf], acc[mf][nf], 0, 0, 0);
    }
#pragma unroll
    for (int mf = 0; mf < 4; ++mf)
#pragma unroll
        for (int nf = 0; nf < 4; ++nf) {
            int col = n0 + nf * 16 + ml;
            float bias = be[col];
#pragma unroll
            for (int r = 0; r < 4; ++r) {
                int row = m0 + mf * 16 + kg * 4 + r;
                att1b[(size_t)row * ATTD + col] = f2bf(acc[mf][nf][r] + bias);
            }
        }
}

// ---------------- per-step K1: att2 + gate + hpart (M=64, K=512, N=4608) ----------------
__global__ __launch_bounds__(256) void k_hsmall(
        const ushort* __restrict__ hbf, const ushort* __restrict__ BpreT,
        const ushort* __restrict__ WTj,
        const float* __restrict__ bd, const float* __restrict__ bfb,
        float* __restrict__ att2, float* __restrict__ gatebuf,
        float* __restrict__ hpart) {
    int blk = blockIdx.x;
    int w = threadIdx.x >> 6, l = threadIdx.x & 63;
    int m = l & 15, kg = l >> 4;
    bool isPre = blk < 40;
    int n = (isPre ? blk * 64 : (blk - 40) * 64) + w * 16 + m;
    const ushort* B = isPre ? (BpreT + (size_t)n * 512) : (WTj + (size_t)n * KX + 2560);
    B += kg * 8;
    const ushort* A = hbf + (size_t)m * 512 + kg * 8;
    f32x4 acc[4] = {};
#pragma unroll 4
    for (int k0 = 0; k0 < 512; k0 += 32) {
        bf16x8 bfr = *(const bf16x8*)(B + k0);
#pragma unroll
        for (int mf = 0; mf < 4; ++mf) {
            bf16x8 afr = *(const bf16x8*)(A + mf * 16 * 512 + k0);
            acc[mf] = __builtin_amdgcn_mfma_f32_16x16x32_bf16(afr, bfr, acc[mf], 0, 0, 0);
        }
    }
    if (isPre) {
        if (n < ATTD) {
            float bias = bd[n];
#pragma unroll
            for (int mf = 0; mf < 4; ++mf)
#pragma unroll
                for (int r = 0; r < 4; ++r) {
                    int b = mf * 16 + kg * 4 + r;
                    att2[(size_t)b * ATTD + n] = acc[mf][r] + bias;
                }
        } else {
            int e = n - ATTD;
            float bias = bfb[e];
#pragma unroll
            for (int mf = 0; mf < 4; ++mf)
#pragma unroll
                for (int r = 0; r < 4; ++r) {
                    int b = mf * 16 + kg * 4 + r;
                    float v = acc[mf][r] + bias;
                    gatebuf[(size_t)b * ENCD + e] = 1.f / (1.f + __expf(-v));
                }
        }
    } else {
#pragma unroll
        for (int mf = 0; mf < 4; ++mf)
#pragma unroll
            for (int r = 0; r < 4; ++r) {
                int b = mf * 16 + kg * 4 + r;
                hpart[(size_t)b * 2048 + n] = acc[mf][r];
            }
    }
}

// ---------------- per-step K2: softmax + context (2 blocks per batch row) ----------------
template<bool BF>
__global__ __launch_bounds__(256) void k_attctx(
        const ushort* __restrict__ att1b, const float* __restrict__ att2,
        const float* __restrict__ vatt, const float* __restrict__ bv,
        const float* __restrict__ gatebuf, const int* __restrict__ lens,
        const float* __restrict__ enc, const ushort* __restrict__ encb,
        ushort* __restrict__ ctxb, float* __restrict__ alpha_out, int t) {
    __shared__ float ev[200];
    __shared__ float inv_s;
    int blk = blockIdx.x;
    int b = blk >> 1, q = blk & 1;
    int tid = threadIdx.x;
    int w = tid >> 6, l = tid & 63;
    float a2r[8], vvr[8];
    const float* att2b = att2 + (size_t)b * ATTD;
#pragma unroll
    for (int i = 0; i < 8; ++i) {
        a2r[i] = att2b[l * 8 + i];
        vvr[i] = vatt[l * 8 + i];
    }
    for (int pp = w; pp < NPIX; pp += 4) {
        const ushort* r = att1b + ((size_t)b * NPIX + pp) * ATTD + l * 8;
        bf16x8 f = *(const bf16x8*)r;
        float s = 0.f;
#pragma unroll
        for (int i = 0; i < 8; ++i)
            s += fmaxf(bf2f((ushort)f[i]) + a2r[i], 0.f) * vvr[i];
        for (int off = 32; off > 0; off >>= 1) s += __shfl_down(s, off);
        if (l == 0) ev[pp] = s + bv[0];
    }
    __syncthreads();
    if (w == 0) {
        float mx = -1e30f;
        for (int pp = l; pp < NPIX; pp += 64) mx = fmaxf(mx, ev[pp]);
        for (int off = 32; off > 0; off >>= 1) mx = fmaxf(mx, __shfl_down(mx, off));
        mx = __shfl(mx, 0);
        float s = 0.f;
        for (int pp = l; pp < NPIX; pp += 64) {
            float e_ = __expf(ev[pp] - mx);
            ev[pp] = e_;
            s += e_;
        }
        for (int off = 32; off > 0; off >>= 1) s += __shfl_down(s, off);
        if (l == 0) inv_s = 1.0f / s;
    }
    __syncthreads();
    float inv = inv_s;
    if (q == 0) {
        bool active = t < (lens[b] - 1);
        for (int pp = tid; pp < NPIX; pp += 256)
            alpha_out[((size_t)b * TSTEPS + t) * NPIX + pp] = active ? ev[pp] * inv : 0.f;
    }
    int e0 = q * 1024 + tid * 4;
    float s0 = 0.f, s1 = 0.f, s2 = 0.f, s3 = 0.f;
    if constexpr (BF) {
        const ushort* ep = encb + (size_t)b * NPIX * ENCD + e0;
#pragma unroll 4
        for (int pp = 0; pp < NPIX; ++pp) {
            ushort4 v = *(const ushort4*)(ep + (size_t)pp * ENCD);
            float al = ev[pp];
            s0 += al * bf2f(v.x); s1 += al * bf2f(v.y);
            s2 += al * bf2f(v.z); s3 += al * bf2f(v.w);
        }
    } else {
        const float* ep = enc + (size_t)b * NPIX * ENCD + e0;
#pragma unroll 4
        for (int pp = 0; pp < NPIX; ++pp) {
            float4 v = *(const float4*)(ep + (size_t)pp * ENCD);
            float al = ev[pp];
            s0 += al * v.x; s1 += al * v.y; s2 += al * v.z; s3 += al * v.w;
        }
    }
    float4 g = *(const float4*)(gatebuf + (size_t)b * ENCD + e0);
    ushort4 o;
    o.x = f2bf(s0 * inv * g.x);
    o.y = f2bf(s1 * inv * g.y);
    o.z = f2bf(s2 * inv * g.z);
    o.w = f2bf(s3 * inv * g.w);
    *(ushort4*)(ctxb + (size_t)b * ENCD + e0) = o;
}

// ---------------- per-step K3: ctx-gates GEMM + LSTM pointwise + hAll ----------------
__global__ __launch_bounds__(256) void k_gatesfin(
        const ushort* __restrict__ ctxb, const ushort* __restrict__ WTj,
        const ushort* __restrict__ embpartb, const float* __restrict__ hpart,
        const float* __restrict__ bih, const float* __restrict__ bhh,
        const int* __restrict__ lens, float* __restrict__ c,
        ushort* __restrict__ hbf, ushort* __restrict__ hAll, int t) {
    __shared__ float gt[64 * 68];
    int g = blockIdx.x;
    int tid = threadIdx.x;
    int w = tid >> 6, l = tid & 63;
    int m = l & 15, kg = l >> 4;
    int jcol = w * 512 + g * 16 + m;
    const ushort* B = WTj + (size_t)jcol * KX + 512 + kg * 8;
    const ushort* A = ctxb + (size_t)m * 2048 + kg * 8;
    f32x4 acc[4] = {};
#pragma unroll 4
    for (int k0 = 0; k0 < 2048; k0 += 32) {
        bf16x8 bfr = *(const bf16x8*)(B + k0);
#pragma unroll
        for (int mf = 0; mf < 4; ++mf) {
            bf16x8 afr = *(const bf16x8*)(A + mf * 16 * 2048 + k0);
            acc[mf] = __builtin_amdgcn_mfma_f32_16x16x32_bf16(afr, bfr, acc[mf], 0, 0, 0);
        }
    }
#pragma unroll
    for (int mf = 0; mf < 4; ++mf)
#pragma unroll
        for (int r = 0; r < 4; ++r)
            gt[(mf * 16 + kg * 4 + r) * 68 + w * 16 + m] = acc[mf][r];
    __syncthreads();
    const ushort* ebase = embpartb + (size_t)t * 64 * 2048;
    for (int idx = tid; idx < 1024; idx += 256) {
        int b = idx >> 4, r = idx & 15;
        int d = g * 16 + r;
        ushort oldh = hbf[(size_t)b * DECD + d];
        ushort houtb = oldh;
        if (t < lens[b] - 1) {
            const ushort* eb = ebase + (size_t)b * 2048;
            const float* hp = hpart + (size_t)b * 2048;
            float gi = gt[b * 68 + r]      + hp[d]        + bf2f(eb[d])        + bih[d]        + bhh[d];
            float gf = gt[b * 68 + 16 + r] + hp[512 + d]  + bf2f(eb[512 + d])  + bih[512 + d]  + bhh[512 + d];
            float gg = gt[b * 68 + 32 + r] + hp[1024 + d] + bf2f(eb[1024 + d]) + bih[1024 + d] + bhh[1024 + d];
            float go = gt[b * 68 + 48 + r] + hp[1536 + d] + bf2f(eb[1536 + d]) + bih[1536 + d] + bhh[1536 + d];
            float cc = c[(size_t)b * DECD + d];
            float si = 1.f / (1.f + __expf(-gi));
            float sf = 1.f / (1.f + __expf(-gf));
            float so = 1.f / (1.f + __expf(-go));
            float cn = sf * cc + si * tanhf(gg);
            float hn = so * tanhf(cn);
            c[(size_t)b * DECD + d] = cn;
            houtb = f2bf(hn);
            hbf[(size_t)b * DECD + d] = houtb;
        }
        hAll[((size_t)t * 64 + b) * 512 + d] = houtb;
    }
}

// ---------------- post-loop: pred = hAll @ WfcT + bfc (masked) ----------------
__global__ __launch_bounds__(256) void k_predall(
        const ushort* __restrict__ hAll, const ushort* __restrict__ WfcT,
        const float* __restrict__ bfc, const int* __restrict__ lens,
        float* __restrict__ pred) {
    int w = threadIdx.x >> 6, l = threadIdx.x & 63;
    int wr = w >> 1, wc = w & 1;
    int m0 = blockIdx.x * 128 + wr * 64;
    int n0 = blockIdx.y * 128 + wc * 64;
    int ml = l & 15, kg = l >> 4;
    const ushort* aBase = hAll + (size_t)(m0 + ml) * 512 + kg * 8;
    const ushort* bBase = WfcT + (size_t)(n0 + ml) * 512 + kg * 8;
    f32x4 acc[4][4] = {};
#pragma unroll 2
    for (int k0 = 0; k0 < 512; k0 += 32) {
        bf16x8 bfr[4], afr[4];
#pragma unroll
        for (int nf = 0; nf < 4; ++nf)
            bfr[nf] = *(const bf16x8*)(bBase + (size_t)nf * 16 * 512 + k0);
#pragma unroll
        for (int mf = 0; mf < 4; ++mf)
            afr[mf] = *(const bf16x8*)(aBase + (size_t)mf * 16 * 512 + k0);
#pragma unroll
        for (int mf = 0; mf < 4; ++mf)
#pragma unroll
            for (int nf = 0; nf < 4; ++nf)
                acc[mf][nf] = __builtin_amdgcn_mfma_f32_16x16x32_bf16(afr[mf], bfr[nf], acc[mf][nf], 0, 0, 0);
    }
#pragma unroll
    for (int mf = 0; mf < 4; ++mf)
#pragma unroll
        for (int nf = 0; nf < 4; ++nf) {
            int col = n0 + nf * 16 + ml;
            if (col < NVOCAB) {
                float bias = bfc[col];
#pragma unroll
                for (int r = 0; r < 4; ++r) {
                    int row = m0 + mf * 16 + kg * 4 + r;
                    int t = row >> 6, b = row & 63;
                    bool act = t < (lens[b] - 1);
                    pred[((size_t)b * TSTEPS + t) * NVOCAB + col] = act ? acc[mf][nf][r] + bias : 0.f;
                }
            }
        }
}

extern "C" void kernel_launch(void* const* d_in, const int* in_sizes, int n_in,
                              void* d_out, int out_size, void* d_ws, size_t ws_size,
                              hipStream_t stream) {
    const float* enc  = (const float*)d_in[0];
    const int*   caps = (const int*)d_in[1];
    const int*   lens = (const int*)d_in[2];
    const float* emb  = (const float*)d_in[3];
    const float* We   = (const float*)d_in[4];
    const float* be   = (const float*)d_in[5];
    const float* Wd   = (const float*)d_in[6];
    const float* bd   = (const float*)d_in[7];
    const float* vatt = (const float*)d_in[8];
    const float* bv   = (const float*)d_in[9];
    const float* Wih  = (const float*)d_in[10];
    const float* bih  = (const float*)d_in[11];
    const float* Whh  = (const float*)d_in[12];
    const float* bhh  = (const float*)d_in[13];
    const float* Winh = (const float*)d_in[14];
    const float* binh = (const float*)d_in[15];
    const float* Winc = (const float*)d_in[16];
    const float* binc = (const float*)d_in[17];
    const float* Wfb  = (const float*)d_in[18];
    const float* bfb  = (const float*)d_in[19];
    const float* Wfc  = (const float*)d_in[20];
    const float* bfc  = (const float*)d_in[21];

    float* out       = (float*)d_out;
    float* pred_out  = out;
    float* cap_out   = out + 15360000;
    float* len_out   = out + 15361600;
    float* alpha_out = out + 15361664;

    char* p = (char*)d_ws;
    ushort* att1b    = (ushort*)p; p += (size_t)12544 * 512 * 2;
    ushort* WTj      = (ushort*)p; p += (size_t)2048 * KX * 2;
    ushort* WfcT     = (ushort*)p; p += (size_t)NPAD * 512 * 2;
    ushort* BpreT    = (ushort*)p; p += (size_t)2560 * 512 * 2;
    ushort* WeT      = (ushort*)p; p += (size_t)512 * 2048 * 2;
    ushort* embAll   = (ushort*)p; p += (size_t)1536 * 512 * 2;
    ushort* embpartb = (ushort*)p; p += (size_t)1536 * 2048 * 2;
    ushort* hAll     = (ushort*)p; p += (size_t)1536 * 512 * 2;
    ushort* ctxb     = (ushort*)p; p += (size_t)64 * 2048 * 2;
    ushort* hbf      = (ushort*)p; p += (size_t)64 * 512 * 2;
    float* att2      = (float*)p;  p += (size_t)64 * 512 * 4;
    float* gatebuf   = (float*)p;  p += (size_t)64 * 2048 * 4;
    float* hpart     = (float*)p;  p += (size_t)64 * 2048 * 4;
    float* c         = (float*)p;  p += (size_t)64 * 512 * 4;
    float* mean      = (float*)p;  p += (size_t)64 * 2048 * 4;
    ushort* encb     = (ushort*)p; p += (size_t)64 * NPIX * ENCD * 2;
    bool useBF = ws_size >= (size_t)(p - (char*)d_ws);

    k_meta<<<7, 256, 0, stream>>>(caps, lens, cap_out, len_out);
    if (useBF) k_encconv<<<12544, 256, 0, stream>>>(enc, encb);
    k_mean<<<dim3(BATCH, 8), 256, 0, stream>>>(enc, mean);
    k_init_hc<<<dim3(16, 4), 256, 0, stream>>>(mean, Winh, binh, Winc, binc, hbf, c);
    k_cp_wtj<<<2048, 256, 0, stream>>>(Wih, Whh, WTj);
    k_tr_bpre<<<dim3(80, 16), 256, 0, stream>>>(Wd, Wfb, BpreT);
    k_tr_wfct<<<dim3(316, 16), 256, 0, stream>>>(Wfc, WfcT);
    k_tr_wet<<<dim3(16, 64), 256, 0, stream>>>(We, WeT);
    k_embgather<<<1536, 256, 0, stream>>>(caps, emb, embAll);
    if (useBF) k_att1<true><<<dim3(98, 4), 256, 0, stream>>>(enc, encb, WeT, be, att1b);
    else       k_att1<false><<<dim3(98, 4), 256, 0, stream>>>(enc, encb, WeT, be, att1b);
    k_embpart<<<dim3(24, 32), 256, 0, stream>>>(embAll, WTj, embpartb);

    for (int t = 0; t < TSTEPS; ++t) {
        k_hsmall<<<72, 256, 0, stream>>>(hbf, BpreT, WTj, bd, bfb, att2, gatebuf, hpart);
        if (useBF)
            k_attctx<true><<<128, 256, 0, stream>>>(att1b, att2, vatt, bv, gatebuf, lens,
                                                    enc, encb, ctxb, alpha_out, t);
        else
            k_attctx<false><<<128, 256, 0, stream>>>(att1b, att2, vatt, bv, gatebuf, lens,
                                                     enc, encb, ctxb, alpha_out, t);
        k_gatesfin<<<32, 256, 0, stream>>>(ctxb, WTj, embpartb, hpart, bih, bhh,
                                           lens, c, hbf, hAll, t);
    }
    k_predall<<<dim3(12, 79), 256, 0, stream>>>(hAll, WfcT, bfc, lens, pred_out);
}

// Round 5
// 2524.997 us; speedup vs baseline: 2.3634x; 1.1451x over previous
//
#include <hip/hip_runtime.h>
#include <hip/hip_bf16.h>

#define BATCH 64
#define NPIX 196
#define ENCD 2048
#define ATTD 512
#define DECD 512
#define EMBD 512
#define NVOCAB 10000
#define TSTEPS 24
#define KX 3072
#define NPAD 10112   // vocab padded to 79*128

typedef short bf16x8 __attribute__((ext_vector_type(8)));
typedef float f32x4 __attribute__((ext_vector_type(4)));

__device__ inline ushort f2bf(float f) {
    union { float f; unsigned u; } v; v.f = f;
    unsigned r = (v.u + 0x7fff + ((v.u >> 16) & 1)) >> 16;
    return (ushort)r;
}
__device__ inline float bf2f(ushort u) {
    union { unsigned u; float f; } v; v.u = ((unsigned)u) << 16;
    return v.f;
}

// ---------------- WTj[j][k] bf16 + meta fused ----------------
__global__ __launch_bounds__(256) void k_cp_wtj(const float* __restrict__ Wih,
                                                const float* __restrict__ Whh,
                                                const int* __restrict__ caps,
                                                const int* __restrict__ lens,
                                                ushort* __restrict__ WTj,
                                                float* __restrict__ cap_out,
                                                float* __restrict__ len_out) {
    int j = blockIdx.x;
    for (int k = threadIdx.x; k < KX; k += 256) {
        float v = (k < 2560) ? Wih[(size_t)j * 2560 + k] : Whh[(size_t)j * 512 + (k - 2560)];
        WTj[(size_t)j * KX + k] = f2bf(v);
    }
    if (blockIdx.x == 0) {
        for (int i = threadIdx.x; i < 1664; i += 256) {
            if (i < 1600) cap_out[i] = (float)caps[i];
            else          len_out[i - 1600] = (float)(lens[i - 1600] - 1);
        }
    }
}

// ---------------- transposes to [n][k] bf16 ----------------
__global__ __launch_bounds__(256) void k_tr_bpre(const float* __restrict__ Wd,
                                                 const float* __restrict__ Wfb,
                                                 ushort* __restrict__ out) {
    __shared__ float tile[32][33];
    int nb = blockIdx.x * 32, kb = blockIdx.y * 32;
    int tx = threadIdx.x & 31, ty = threadIdx.x >> 5;
    for (int i = 0; i < 32; i += 8) {
        int k = kb + ty + i, n = nb + tx;
        float v = (n < ATTD) ? Wd[(size_t)k * ATTD + n] : Wfb[(size_t)k * ENCD + (n - ATTD)];
        tile[ty + i][tx] = v;
    }
    __syncthreads();
    for (int i = 0; i < 32; i += 8)
        out[(size_t)(nb + ty + i) * 512 + kb + tx] = f2bf(tile[tx][ty + i]);
}

__global__ __launch_bounds__(256) void k_tr_wfct(const float* __restrict__ Wfc,
                                                 ushort* __restrict__ out) {
    __shared__ float tile[32][33];
    int nb = blockIdx.x * 32, kb = blockIdx.y * 32;
    int tx = threadIdx.x & 31, ty = threadIdx.x >> 5;
    for (int i = 0; i < 32; i += 8) {
        int k = kb + ty + i, n = nb + tx;
        float v = (n < NVOCAB) ? Wfc[(size_t)k * NVOCAB + n] : 0.f;
        tile[ty + i][tx] = v;
    }
    __syncthreads();
    for (int i = 0; i < 32; i += 8)
        out[(size_t)(nb + ty + i) * 512 + kb + tx] = f2bf(tile[tx][ty + i]);
}

__global__ __launch_bounds__(256) void k_tr_wet(const float* __restrict__ We,
                                                ushort* __restrict__ out) {
    __shared__ float tile[32][33];
    int nb = blockIdx.x * 32, kb = blockIdx.y * 32;
    int tx = threadIdx.x & 31, ty = threadIdx.x >> 5;
    for (int i = 0; i < 32; i += 8) {
        int k = kb + ty + i, n = nb + tx;
        tile[ty + i][tx] = We[(size_t)k * ATTD + n];
    }
    __syncthreads();
    for (int i = 0; i < 32; i += 8)
        out[(size_t)(nb + ty + i) * ENCD + kb + tx] = f2bf(tile[tx][ty + i]);
}

// ---------------- embpart (bf16) = gathered emb @ WTj[:, :512]^T ----------------
__global__ __launch_bounds__(256) void k_embpart(const int* __restrict__ caps,
                                                 const float* __restrict__ emb,
                                                 const ushort* __restrict__ WTj,
                                                 ushort* __restrict__ embpartb) {
    int w = threadIdx.x >> 6, l = threadIdx.x & 63;
    int m = l & 15, kg = l >> 4;
    int r0 = blockIdx.x * 64;
    int n = blockIdx.y * 64 + w * 16 + m;
    const ushort* B = WTj + (size_t)n * KX + kg * 8;
    int tok[4];
#pragma unroll
    for (int mf = 0; mf < 4; ++mf) {
        int row = r0 + m + mf * 16;
        tok[mf] = caps[(row & 63) * 25 + (row >> 6)];
    }
    f32x4 acc[4] = {};
#pragma unroll 4
    for (int k0 = 0; k0 < 512; k0 += 32) {
        bf16x8 bfr = *(const bf16x8*)(B + k0);
#pragma unroll
        for (int mf = 0; mf < 4; ++mf) {
            const float* ap = emb + (size_t)tok[mf] * 512 + kg * 8 + k0;
            float4 f0 = *(const float4*)ap;
            float4 f1 = *(const float4*)(ap + 4);
            bf16x8 a;
            a[0] = f2bf(f0.x); a[1] = f2bf(f0.y); a[2] = f2bf(f0.z); a[3] = f2bf(f0.w);
            a[4] = f2bf(f1.x); a[5] = f2bf(f1.y); a[6] = f2bf(f1.z); a[7] = f2bf(f1.w);
            acc[mf] = __builtin_amdgcn_mfma_f32_16x16x32_bf16(a, bfr, acc[mf], 0, 0, 0);
        }
    }
#pragma unroll
    for (int mf = 0; mf < 4; ++mf)
#pragma unroll
        for (int r = 0; r < 4; ++r)
            embpartb[(size_t)(r0 + mf * 16 + kg * 4 + r) * 2048 + n] = f2bf(acc[mf][r]);
}

// ---------------- enc fp32 -> bf16 ----------------
__global__ void k_encconv(const float* __restrict__ enc, ushort* __restrict__ encb) {
    size_t i = ((size_t)blockIdx.x * 256 + threadIdx.x) * 8;
    float4 f0 = *(const float4*)(enc + i);
    float4 f1 = *(const float4*)(enc + i + 4);
    union { bf16x8 v; ushort u[8]; } o;
    o.u[0] = f2bf(f0.x); o.u[1] = f2bf(f0.y); o.u[2] = f2bf(f0.z); o.u[3] = f2bf(f0.w);
    o.u[4] = f2bf(f1.x); o.u[5] = f2bf(f1.y); o.u[6] = f2bf(f1.z); o.u[7] = f2bf(f1.w);
    *(bf16x8*)(encb + i) = o.v;
}

// ---------------- mean over 196 positions (bf16 in/out) ----------------
__global__ __launch_bounds__(256) void k_meanb(const ushort* __restrict__ encb,
                                               ushort* __restrict__ meanb) {
    int b = blockIdx.x, half = blockIdx.y;
    int e0 = half * 1024 + threadIdx.x * 4;
    const ushort* ep = encb + (size_t)b * NPIX * ENCD + e0;
    float s0 = 0.f, s1 = 0.f, s2 = 0.f, s3 = 0.f;
#pragma unroll 4
    for (int p = 0; p < NPIX; ++p) {
        ushort4 v = *(const ushort4*)(ep + (size_t)p * ENCD);
        s0 += bf2f(v.x); s1 += bf2f(v.y); s2 += bf2f(v.z); s3 += bf2f(v.w);
    }
    const float sc = 1.0f / NPIX;
    ushort4 o;
    o.x = f2bf(s0 * sc); o.y = f2bf(s1 * sc); o.z = f2bf(s2 * sc); o.w = f2bf(s3 * sc);
    *(ushort4*)(meanb + (size_t)b * ENCD + e0) = o;
}

// ---------------- h0/c0 init partials: K-split 8, atomic accumulate ----------------
__global__ __launch_bounds__(256) void k_initp(
        const ushort* __restrict__ meanb,
        const float* __restrict__ Wh, const float* __restrict__ Wc,
        float* __restrict__ hcacc) {
    __shared__ float mm[4][256];
    int bg = blockIdx.x * 4;
    int jy = blockIdx.y;
    int kz = blockIdx.z;
    int tid = threadIdx.x;
    for (int i = tid; i < 1024; i += 256) {
        int qq = i >> 8, k = i & 255;
        mm[qq][k] = bf2f(meanb[(size_t)(bg + qq) * ENCD + kz * 256 + k]);
    }
    __syncthreads();
    int j = jy * 256 + tid;   // 0..1023
    const float* W; int col;
    if (j < 512) { W = Wh; col = j; } else { W = Wc; col = j - 512; }
    W += (size_t)(kz * 256) * 512 + col;
    float acc[4] = {};
    for (int k = 0; k < 256; ++k) {
        float w = W[(size_t)k * 512];
#pragma unroll
        for (int qq = 0; qq < 4; ++qq) acc[qq] += mm[qq][k] * w;
    }
#pragma unroll
    for (int qq = 0; qq < 4; ++qq)
        atomicAdd(hcacc + (size_t)(bg + qq) * 1024 + j, acc[qq]);
}

__global__ __launch_bounds__(256) void k_initfin(
        const float* __restrict__ hcacc, const float* __restrict__ bh,
        const float* __restrict__ bc, ushort* __restrict__ hbf,
        float* __restrict__ c) {
    int base = blockIdx.x * 2048;
    for (int i = threadIdx.x; i < 2048; i += 256) {
        int idx = base + i;
        int b = idx >> 10, n = idx & 1023;
        float v = hcacc[idx];
        if (n < 512) hbf[(size_t)b * 512 + n] = f2bf(v + bh[n]);
        else         c[(size_t)b * 512 + (n - 512)] = v + bc[n - 512];
    }
}

// ---------------- one-time: att1 = enc @ We + be (bf16 MFMA) ----------------
__global__ __launch_bounds__(256) void k_att1(
        const ushort* __restrict__ encb, const ushort* __restrict__ WeT,
        const float* __restrict__ be, ushort* __restrict__ att1b) {
    int w = threadIdx.x >> 6, l = threadIdx.x & 63;
    int wr = w >> 1, wc = w & 1;
    int m0 = blockIdx.x * 128 + wr * 64;
    int n0 = blockIdx.y * 128 + wc * 64;
    int ml = l & 15, kg = l >> 4;
    const ushort* aBase = encb + (size_t)(m0 + ml) * ENCD + kg * 8;
    const ushort* bBase = WeT + (size_t)(n0 + ml) * ENCD + kg * 8;
    f32x4 acc[4][4] = {};
    for (int k0 = 0; k0 < ENCD; k0 += 32) {
        bf16x8 bfr[4], afr[4];
#pragma unroll
        for (int nf = 0; nf < 4; ++nf)
            bfr[nf] = *(const bf16x8*)(bBase + (size_t)nf * 16 * ENCD + k0);
#pragma unroll
        for (int mf = 0; mf < 4; ++mf)
            afr[mf] = *(const bf16x8*)(aBase + (size_t)mf * 16 * ENCD + k0);
#pragma unroll
        for (int mf = 0; mf < 4; ++mf)
#pragma unroll
            for (int nf = 0; nf < 4; ++nf)
                acc[mf][nf] = __builtin_amdgcn_mfma_f32_16x16x32_bf16(afr[mf], bfr[nf], acc[mf][nf], 0, 0, 0);
    }
#pragma unroll
    for (int mf = 0; mf < 4; ++mf)
#pragma unroll
        for (int nf = 0; nf < 4; ++nf) {
            int col = n0 + nf * 16 + ml;
            float bias = be[col];
#pragma unroll
            for (int r = 0; r < 4; ++r) {
                int row = m0 + mf * 16 + kg * 4 + r;
                att1b[(size_t)row * ATTD + col] = f2bf(acc[mf][nf][r] + bias);
            }
        }
}

// ---------------- per-step K1: att2 + gate + hpart; 8 waves, K-split 2 ----------------
__global__ __launch_bounds__(512) void k_hsmall(
        const ushort* __restrict__ hbf, const ushort* __restrict__ BpreT,
        const ushort* __restrict__ WTj,
        const float* __restrict__ bd, const float* __restrict__ bfb,
        float* __restrict__ att2, ushort* __restrict__ gateb,
        float* __restrict__ hpart) {
    __shared__ float part[2][64][68];
    int blk = blockIdx.x;
    int tid = threadIdx.x;
    int w = tid >> 6, l = tid & 63;
    int wq = w & 3, kh = w >> 2;
    int m = l & 15, kg = l >> 4;
    bool isPre = blk < 40;
    int nt = isPre ? blk : blk - 40;
    int n = nt * 64 + wq * 16 + m;
    const ushort* B = isPre ? (BpreT + (size_t)n * 512) : (WTj + (size_t)n * KX + 2560);
    B += kh * 256 + kg * 8;
    const ushort* A = hbf + (size_t)m * 512 + kh * 256 + kg * 8;
    f32x4 acc[4] = {};
#pragma unroll
    for (int k0 = 0; k0 < 256; k0 += 32) {
        bf16x8 bfr = *(const bf16x8*)(B + k0);
#pragma unroll
        for (int mf = 0; mf < 4; ++mf) {
            bf16x8 afr = *(const bf16x8*)(A + mf * 16 * 512 + k0);
            acc[mf] = __builtin_amdgcn_mfma_f32_16x16x32_bf16(afr, bfr, acc[mf], 0, 0, 0);
        }
    }
#pragma unroll
    for (int mf = 0; mf < 4; ++mf)
#pragma unroll
        for (int r = 0; r < 4; ++r)
            part[kh][mf * 16 + kg * 4 + r][wq * 16 + m] = acc[mf][r];
    __syncthreads();
    for (int idx = tid; idx < 4096; idx += 512) {
        int b = idx >> 6, nn = idx & 63;
        float v = part[0][b][nn] + part[1][b][nn];
        if (isPre) {
            int ng = blk * 64 + nn;
            if (ng < 512) att2[(size_t)b * 512 + ng] = v + bd[ng];
            else {
                int e = ng - 512;
                gateb[(size_t)b * 2048 + e] = f2bf(1.f / (1.f + __expf(-(v + bfb[e]))));
            }
        } else {
            hpart[(size_t)b * 2048 + (blk - 40) * 64 + nn] = v;
        }
    }
}

// ---------------- per-step K2: softmax + context; 512 thr, p-split 2 ----------------
__global__ __launch_bounds__(512) void k_attctx(
        const ushort* __restrict__ att1b, const float* __restrict__ att2,
        const float* __restrict__ vatt, const float* __restrict__ bv,
        const ushort* __restrict__ gateb, const int* __restrict__ lens,
        const ushort* __restrict__ encb,
        ushort* __restrict__ ctxb, float* __restrict__ alpha_out, int t) {
    __shared__ float ev[200];
    __shared__ float cpart[2][1024];
    __shared__ float inv_s;
    int blk = blockIdx.x;
    int b = blk >> 1, q = blk & 1;
    int tid = threadIdx.x;
    int w = tid >> 6, l = tid & 63;
    float a2r[8], vvr[8];
    const float* att2b = att2 + (size_t)b * ATTD;
#pragma unroll
    for (int i = 0; i < 8; ++i) {
        a2r[i] = att2b[l * 8 + i];
        vvr[i] = vatt[l * 8 + i];
    }
    for (int pp = w; pp < NPIX; pp += 8) {
        bf16x8 f = *(const bf16x8*)(att1b + ((size_t)b * NPIX + pp) * ATTD + l * 8);
        float s = 0.f;
#pragma unroll
        for (int i = 0; i < 8; ++i)
            s += fmaxf(bf2f((ushort)f[i]) + a2r[i], 0.f) * vvr[i];
        for (int off = 32; off > 0; off >>= 1) s += __shfl_down(s, off);
        if (l == 0) ev[pp] = s + bv[0];
    }
    __syncthreads();
    if (w == 0) {
        float mx = -1e30f;
        for (int pp = l; pp < NPIX; pp += 64) mx = fmaxf(mx, ev[pp]);
        for (int off = 32; off > 0; off >>= 1) mx = fmaxf(mx, __shfl_down(mx, off));
        mx = __shfl(mx, 0);
        float s = 0.f;
        for (int pp = l; pp < NPIX; pp += 64) {
            float e_ = __expf(ev[pp] - mx);
            ev[pp] = e_;
            s += e_;
        }
        for (int off = 32; off > 0; off >>= 1) s += __shfl_down(s, off);
        if (l == 0) inv_s = 1.0f / s;
    }
    __syncthreads();
    float inv = inv_s;
    if (q == 0) {
        bool active = t < (lens[b] - 1);
        for (int pp = tid; pp < NPIX; pp += 512)
            alpha_out[((size_t)b * TSTEPS + t) * NPIX + pp] = active ? ev[pp] * inv : 0.f;
    }
    int pg = tid >> 8, th = tid & 255;
    int e0 = q * 1024 + th * 4;
    const ushort* ep = encb + (size_t)b * NPIX * ENCD + (size_t)pg * 98 * ENCD + e0;
    float s0 = 0.f, s1 = 0.f, s2 = 0.f, s3 = 0.f;
#pragma unroll 2
    for (int pp = 0; pp < 98; ++pp) {
        ushort4 v = *(const ushort4*)(ep + (size_t)pp * ENCD);
        float al = ev[pg * 98 + pp];
        s0 += al * bf2f(v.x); s1 += al * bf2f(v.y);
        s2 += al * bf2f(v.z); s3 += al * bf2f(v.w);
    }
    *(float4*)&cpart[pg][th * 4] = make_float4(s0, s1, s2, s3);
    __syncthreads();
    if (tid < 256) {
        int e = q * 1024 + tid * 4;
        ushort4 g4 = *(const ushort4*)(gateb + (size_t)b * 2048 + e);
        ushort4 o;
        o.x = f2bf((cpart[0][tid * 4 + 0] + cpart[1][tid * 4 + 0]) * inv * bf2f(g4.x));
        o.y = f2bf((cpart[0][tid * 4 + 1] + cpart[1][tid * 4 + 1]) * inv * bf2f(g4.y));
        o.z = f2bf((cpart[0][tid * 4 + 2] + cpart[1][tid * 4 + 2]) * inv * bf2f(g4.z));
        o.w = f2bf((cpart[0][tid * 4 + 3] + cpart[1][tid * 4 + 3]) * inv * bf2f(g4.w));
        *(ushort4*)(ctxb + (size_t)b * 2048 + e) = o;
    }
}

// ---------------- per-step K3: ctx-gates GEMM (8 waves, K-split 2) + LSTM ----------------
__global__ __launch_bounds__(512) void k_gatesfin(
        const ushort* __restrict__ ctxb, const ushort* __restrict__ WTj,
        const ushort* __restrict__ embpartb, const float* __restrict__ hpart,
        const float* __restrict__ bih, const float* __restrict__ bhh,
        const int* __restrict__ lens, float* __restrict__ c,
        ushort* __restrict__ hbf, ushort* __restrict__ hAll, int t) {
    __shared__ float gt[2][64][68];
    int g = blockIdx.x;
    int tid = threadIdx.x;
    int w = tid >> 6, l = tid & 63;
    int gate = w & 3, kh = w >> 2;
    int m = l & 15, kg = l >> 4;
    int jcol = gate * 512 + g * 16 + m;
    const ushort* B = WTj + (size_t)jcol * KX + 512 + kh * 1024 + kg * 8;
    const ushort* A = ctxb + (size_t)m * 2048 + kh * 1024 + kg * 8;
    f32x4 acc[4] = {};
#pragma unroll 4
    for (int k0 = 0; k0 < 1024; k0 += 32) {
        bf16x8 bfr = *(const bf16x8*)(B + k0);
#pragma unroll
        for (int mf = 0; mf < 4; ++mf) {
            bf16x8 afr = *(const bf16x8*)(A + mf * 16 * 2048 + k0);
            acc[mf] = __builtin_amdgcn_mfma_f32_16x16x32_bf16(afr, bfr, acc[mf], 0, 0, 0);
        }
    }
#pragma unroll
    for (int mf = 0; mf < 4; ++mf)
#pragma unroll
        for (int r = 0; r < 4; ++r)
            gt[kh][mf * 16 + kg * 4 + r][gate * 16 + m] = acc[mf][r];
    __syncthreads();
    const ushort* ebase = embpartb + (size_t)t * 64 * 2048;
    for (int idx = tid; idx < 1024; idx += 512) {
        int b = idx >> 4, r = idx & 15;
        int d = g * 16 + r;
        ushort houtb = hbf[(size_t)b * DECD + d];
        if (t < lens[b] - 1) {
            const ushort* eb = ebase + (size_t)b * 2048;
            const float* hp = hpart + (size_t)b * 2048;
            float gi = gt[0][b][r]      + gt[1][b][r]      + hp[d]        + bf2f(eb[d])        + bih[d]        + bhh[d];
            float gf = gt[0][b][16 + r] + gt[1][b][16 + r] + hp[512 + d]  + bf2f(eb[512 + d])  + bih[512 + d]  + bhh[512 + d];
            float gg = gt[0][b][32 + r] + gt[1][b][32 + r] + hp[1024 + d] + bf2f(eb[1024 + d]) + bih[1024 + d] + bhh[1024 + d];
            float go = gt[0][b][48 + r] + gt[1][b][48 + r] + hp[1536 + d] + bf2f(eb[1536 + d]) + bih[1536 + d] + bhh[1536 + d];
            float cc = c[(size_t)b * DECD + d];
            float si = 1.f / (1.f + __expf(-gi));
            float sf = 1.f / (1.f + __expf(-gf));
            float so = 1.f / (1.f + __expf(-go));
            float cn = sf * cc + si * tanhf(gg);
            float hn = so * tanhf(cn);
            c[(size_t)b * DECD + d] = cn;
            houtb = f2bf(hn);
            hbf[(size_t)b * DECD + d] = houtb;
        }
        hAll[((size_t)t * 64 + b) * 512 + d] = houtb;
    }
}

// ---------------- post-loop: pred = hAll @ WfcT + bfc (masked) ----------------
__global__ __launch_bounds__(256) void k_predall(
        const ushort* __restrict__ hAll, const ushort* __restrict__ WfcT,
        const float* __restrict__ bfc, const int* __restrict__ lens,
        float* __restrict__ pred) {
    int w = threadIdx.x >> 6, l = threadIdx.x & 63;
    int wr = w >> 1, wc = w & 1;
    int m0 = blockIdx.x * 128 + wr * 64;
    int n0 = blockIdx.y * 128 + wc * 64;
    int ml = l & 15, kg = l >> 4;
    const ushort* aBase = hAll + (size_t)(m0 + ml) * 512 + kg * 8;
    const ushort* bBase = WfcT + (size_t)(n0 + ml) * 512 + kg * 8;
    f32x4 acc[4][4] = {};
#pragma unroll 2
    for (int k0 = 0; k0 < 512; k0 += 32) {
        bf16x8 bfr[4], afr[4];
#pragma unroll
        for (int nf = 0; nf < 4; ++nf)
            bfr[nf] = *(const bf16x8*)(bBase + (size_t)nf * 16 * 512 + k0);
#pragma unroll
        for (int mf = 0; mf < 4; ++mf)
            afr[mf] = *(const bf16x8*)(aBase + (size_t)mf * 16 * 512 + k0);
#pragma unroll
        for (int mf = 0; mf < 4; ++mf)
#pragma unroll
            for (int nf = 0; nf < 4; ++nf)
                acc[mf][nf] = __builtin_amdgcn_mfma_f32_16x16x32_bf16(afr[mf], bfr[nf], acc[mf][nf], 0, 0, 0);
    }
#pragma unroll
    for (int mf = 0; mf < 4; ++mf)
#pragma unroll
        for (int nf = 0; nf < 4; ++nf) {
            int col = n0 + nf * 16 + ml;
            if (col < NVOCAB) {
                float bias = bfc[col];
#pragma unroll
                for (int r = 0; r < 4; ++r) {
                    int row = m0 + mf * 16 + kg * 4 + r;
                    int t = row >> 6, b = row & 63;
                    bool act = t < (lens[b] - 1);
                    pred[((size_t)b * TSTEPS + t) * NVOCAB + col] = act ? acc[mf][nf][r] + bias : 0.f;
                }
            }
        }
}

extern "C" void kernel_launch(void* const* d_in, const int* in_sizes, int n_in,
                              void* d_out, int out_size, void* d_ws, size_t ws_size,
                              hipStream_t stream) {
    const float* enc  = (const float*)d_in[0];
    const int*   caps = (const int*)d_in[1];
    const int*   lens = (const int*)d_in[2];
    const float* emb  = (const float*)d_in[3];
    const float* We   = (const float*)d_in[4];
    const float* be   = (const float*)d_in[5];
    const float* Wd   = (const float*)d_in[6];
    const float* bd   = (const float*)d_in[7];
    const float* vatt = (const float*)d_in[8];
    const float* bv   = (const float*)d_in[9];
    const float* Wih  = (const float*)d_in[10];
    const float* bih  = (const float*)d_in[11];
    const float* Whh  = (const float*)d_in[12];
    const float* bhh  = (const float*)d_in[13];
    const float* Winh = (const float*)d_in[14];
    const float* binh = (const float*)d_in[15];
    const float* Winc = (const float*)d_in[16];
    const float* binc = (const float*)d_in[17];
    const float* Wfb  = (const float*)d_in[18];
    const float* bfb  = (const float*)d_in[19];
    const float* Wfc  = (const float*)d_in[20];
    const float* bfc  = (const float*)d_in[21];

    float* out       = (float*)d_out;
    float* pred_out  = out;
    float* cap_out   = out + 15360000;
    float* len_out   = out + 15361600;
    float* alpha_out = out + 15361664;

    char* p = (char*)d_ws;
    ushort* att1b    = (ushort*)p; p += (size_t)12544 * 512 * 2;
    ushort* WTj      = (ushort*)p; p += (size_t)2048 * KX * 2;
    ushort* WfcT     = (ushort*)p; p += (size_t)NPAD * 512 * 2;
    ushort* BpreT    = (ushort*)p; p += (size_t)2560 * 512 * 2;
    ushort* WeT      = (ushort*)p; p += (size_t)512 * 2048 * 2;
    ushort* embpartb = (ushort*)p; p += (size_t)1536 * 2048 * 2;
    ushort* hAll     = (ushort*)p; p += (size_t)1536 * 512 * 2;
    ushort* ctxb     = (ushort*)p; p += (size_t)64 * 2048 * 2;   // aliased: hcacc (fp32 64x1024)
    ushort* hbf      = (ushort*)p; p += (size_t)64 * 512 * 2;
    float* att2      = (float*)p;  p += (size_t)64 * 512 * 4;
    ushort* gateb    = (ushort*)p; p += (size_t)64 * 2048 * 2;
    float* hpart     = (float*)p;  p += (size_t)64 * 2048 * 4;
    float* c         = (float*)p;  p += (size_t)64 * 512 * 4;
    ushort* meanb    = (ushort*)p; p += (size_t)64 * 2048 * 2;
    ushort* encb     = (ushort*)p; p += (size_t)64 * NPIX * ENCD * 2;
    float* hcacc     = (float*)ctxb;

    // -- weight prep (fp32 reads happen before encb conversion) --
    k_cp_wtj<<<2048, 256, 0, stream>>>(Wih, Whh, caps, lens, WTj, cap_out, len_out);
    k_tr_bpre<<<dim3(80, 16), 256, 0, stream>>>(Wd, Wfb, BpreT);
    k_tr_wfct<<<dim3(316, 16), 256, 0, stream>>>(Wfc, WfcT);
    k_tr_wet<<<dim3(16, 64), 256, 0, stream>>>(We, WeT);
    k_embpart<<<dim3(24, 32), 256, 0, stream>>>(caps, emb, WTj, embpartb);
    hipMemsetAsync(hcacc, 0, (size_t)64 * 1024 * 4, stream);
    // -- enc conversion + init (encb stays L3-hot into the loop) --
    k_encconv<<<12544, 256, 0, stream>>>(enc, encb);
    k_meanb<<<dim3(64, 2), 256, 0, stream>>>(encb, meanb);
    k_initp<<<dim3(16, 4, 8), 256, 0, stream>>>(meanb, Winh, Winc, hcacc);
    k_initfin<<<32, 256, 0, stream>>>(hcacc, binh, binc, hbf, c);
    k_att1<<<dim3(98, 4), 256, 0, stream>>>(encb, WeT, be, att1b);

    for (int t = 0; t < TSTEPS; ++t) {
        k_hsmall<<<72, 512, 0, stream>>>(hbf, BpreT, WTj, bd, bfb, att2, gateb, hpart);
        k_attctx<<<128, 512, 0, stream>>>(att1b, att2, vatt, bv, gateb, lens,
                                          encb, ctxb, alpha_out, t);
        k_gatesfin<<<32, 512, 0, stream>>>(ctxb, WTj, embpartb, hpart, bih, bhh,
                                           lens, c, hbf, hAll, t);
    }
    k_predall<<<dim3(12, 79), 256, 0, stream>>>(hAll, WfcT, bfc, lens, pred_out);
}